// Round 12
// baseline (204.153 us; speedup 1.0000x reference)
//
#include <hip/hip_runtime.h>

typedef _Float16 hf;
typedef _Float16 half2v __attribute__((ext_vector_type(2)));
typedef _Float16 half8 __attribute__((ext_vector_type(8)));
typedef float f32x4 __attribute__((ext_vector_type(4)));
typedef int int4v __attribute__((ext_vector_type(4)));

constexpr int Steps = 27;

// ws half-index layout:
//   wrec : [0, 393216)         (((cls*16+wv)*3+j)*8+ks)*512 + lane*8 + jj
//          wave wv<8: row gates {u_r,o_r,i_r}; wv>=8: col gates {u_c,o_c,i_c}; d=(wv&7)*16+..
//   wx   : [393216, 589824)    (((cls*6+g)*8+wv)*4+ks)*512 + lane*8 + j   K=[256,384)
//   fc3  : [589824, 598016)
//   fc4  : [598016, 614400)
//   xWb  : [614400, +18874368)  [cls][bn][cell][d*6 + pos], pos: 0,1,2=u_r,o_r,i_r; 3,4,5=u_c,o_c,i_c
constexpr int OFF_WX = 393216;
constexpr int OFF_F3 = 589824;
constexpr int OFF_F4 = 598016;
constexpr int OFF_XW = 614400;

__device__ __forceinline__ int aidx(int r, int k) {  // halfs, K=256 (witran A)
  int blk = k >> 3;
  return r * 256 + (((blk ^ (r & 7)) & 31) << 3) + (k & 7);
}
__device__ __forceinline__ int hidx(int r, int k) {  // halfs, K=128 (prelude h buffers)
  int blk = k >> 3;
  return r * 128 + (((blk ^ (r & 15)) & 15) << 3) + (k & 7);
}
__device__ __forceinline__ int xidx(int r, int k) {  // halfs, K=64 (prelude x)
  int blk = k >> 3;
  return r * 64 + (((blk ^ (r & 7)) & 7) << 3) + (k & 7);
}
__device__ __forceinline__ float sigmoidf_(float x) { return 1.0f / (1.0f + __expf(-x)); }
__device__ __forceinline__ float tanh_(float x) { return 1.0f - 2.0f / (__expf(2.0f * x) + 1.0f); }
__device__ __forceinline__ float lo16f(unsigned v) {
  return (float)__builtin_bit_cast(half2v, v)[0];
}
__device__ __forceinline__ float hi16f(unsigned v) {
  return (float)__builtin_bit_cast(half2v, v)[1];
}

// ---- kernel 1: all weights -> fragment-ordered fp16 ----
__global__ __launch_bounds__(512) void prep(const float* __restrict__ fc3_w,
                                            const float* __restrict__ fc4_w,
                                            const float* __restrict__ W_enc,
                                            hf* __restrict__ wsh) {
  int idx = blockIdx.x * 512 + threadIdx.x;
  if (idx >= OFF_XW) return;
  float v;
  if (idx < OFF_WX) {  // recurrent W, gate-triple per wave
    int jj = idx & 7, lane = (idx >> 3) & 63, rest = idx >> 9;
    int ks = rest & 7; rest >>= 3;
    int j = rest % 3; rest /= 3;
    int wv = rest & 15, cls = rest >> 4;
    int gate = (wv < 8) ? (j < 2 ? j : 4) : (j < 2 ? j + 2 : 5);  // {0,1,4} / {2,3,5}
    int n = gate * 128 + (wv & 7) * 16 + (lane & 15);
    int k = ks * 32 + ((lane >> 4) << 3) + jj;
    v = W_enc[(cls * 768 + n) * 384 + k];
  } else if (idx < OFF_F3) {  // x-part Wx
    int f = idx - OFF_WX;
    int j = f & 7, lane = (f >> 3) & 63, rest = f >> 9;
    int ks = rest & 3; rest >>= 2;
    int wv = rest & 7; rest >>= 3;
    int gate = rest % 6, cls = rest / 6;
    int n = gate * 128 + wv * 16 + (lane & 15);
    int k = 256 + ks * 32 + ((lane >> 4) << 3) + j;
    v = W_enc[(cls * 768 + n) * 384 + k];
  } else if (idx < OFF_F4) {  // fc3
    int f = idx - OFF_F3;
    int j = f & 7, lane = (f >> 3) & 63, rest = f >> 9;
    int ks = rest & 1, wv = rest >> 1;
    int n = wv * 16 + (lane & 15), k = ks * 32 + ((lane >> 4) << 3) + j;
    v = fc3_w[n * 64 + k];
  } else {  // fc4
    int f = idx - OFF_F4;
    int j = f & 7, lane = (f >> 3) & 63, rest = f >> 9;
    int ks = rest & 3, wv = rest >> 2;
    int n = wv * 16 + (lane & 15), k = ks * 32 + ((lane >> 4) << 3) + j;
    v = fc4_w[n * 128 + k];
  }
  wsh[idx] = (hf)v;
}

// ---- kernel 2: frontend MLP + xW precompute; xWb pos-ordered, coalesced store ----
__global__ __launch_bounds__(512) void prelude(
    const float* __restrict__ x, const float* __restrict__ fc3_b, const float* __restrict__ fc4_b,
    const float* __restrict__ B_enc, const hf* __restrict__ wsh, hf* __restrict__ xWb) {
  const int t = threadIdx.x, lane = t & 63, wv = t >> 6;
  const int c16 = lane & 15, quad = lane >> 4;
  const int row0 = blockIdx.x * 64, bn = row0 / 192, l0 = row0 % 192;
  const int d = wv * 16 + c16;

  __shared__ __attribute__((aligned(16))) hf xA[64 * 64];
  __shared__ __attribute__((aligned(16))) hf hbuf[64 * 128];
  __shared__ __attribute__((aligned(16))) hf xout[64 * 768];
  __shared__ float actf[64];

  {  // stage x -> fp16 swizzled LDS
    int r = t >> 3, cb = (t & 7) * 8;
    const float* xp = x + (size_t)(row0 + r) * 64 + cb;
    f32x4 a = *(const f32x4*)xp, b = *(const f32x4*)(xp + 4);
    half8 h;
    h[0] = (hf)a.x; h[1] = (hf)a.y; h[2] = (hf)a.z; h[3] = (hf)a.w;
    h[4] = (hf)b.x; h[5] = (hf)b.y; h[6] = (hf)b.z; h[7] = (hf)b.w;
    *(half8*)&xA[xidx(r, cb)] = h;
  }
  if (t < 64) {
    int l = l0 + t;
    actf[t] = ((l / 12) + (l % 12)) < 12 ? 1.f : 0.f;
  }
  __syncthreads();

  // fc3
  {
    float b3v = fc3_b[d];
    half8 w0 = *(const half8*)(wsh + OFF_F3 + (wv * 2 + 0) * 512 + lane * 8);
    half8 w1 = *(const half8*)(wsh + OFF_F3 + (wv * 2 + 1) * 512 + lane * 8);
    f32x4 acc[4] = {{0, 0, 0, 0}, {0, 0, 0, 0}, {0, 0, 0, 0}, {0, 0, 0, 0}};
#pragma unroll
    for (int mt = 0; mt < 4; ++mt) {
      half8 a0 = *(const half8*)&xA[xidx(mt * 16 + c16, quad * 8)];
      half8 a1 = *(const half8*)&xA[xidx(mt * 16 + c16, 32 + quad * 8)];
      acc[mt] = __builtin_amdgcn_mfma_f32_16x16x32_f16(a0, w0, acc[mt], 0, 0, 0);
      acc[mt] = __builtin_amdgcn_mfma_f32_16x16x32_f16(a1, w1, acc[mt], 0, 0, 0);
    }
#pragma unroll
    for (int mt = 0; mt < 4; ++mt)
#pragma unroll
      for (int r = 0; r < 4; ++r)
        hbuf[hidx(mt * 16 + quad * 4 + r, d)] = (hf)fmaxf(acc[mt][r] + b3v, 0.f);
  }
  __syncthreads();

  // fc4
  {
    float b4v = fc4_b[d];
    half8 w4[4];
#pragma unroll
    for (int ks = 0; ks < 4; ++ks)
      w4[ks] = *(const half8*)(wsh + OFF_F4 + (wv * 4 + ks) * 512 + lane * 8);
    f32x4 acc[4] = {{0, 0, 0, 0}, {0, 0, 0, 0}, {0, 0, 0, 0}, {0, 0, 0, 0}};
#pragma unroll
    for (int mt = 0; mt < 4; ++mt)
#pragma unroll
      for (int ks = 0; ks < 4; ++ks) {
        half8 a = *(const half8*)&hbuf[hidx(mt * 16 + c16, ks * 32 + quad * 8)];
        acc[mt] = __builtin_amdgcn_mfma_f32_16x16x32_f16(a, w4[ks], acc[mt], 0, 0, 0);
      }
    __syncthreads();
#pragma unroll
    for (int mt = 0; mt < 4; ++mt)
#pragma unroll
      for (int r = 0; r < 4; ++r)
        hbuf[hidx(mt * 16 + quad * 4 + r, d)] = (hf)(acc[mt][r] + b4v);
  }
  __syncthreads();

  // xW: per orig-gate g, store into pos {0,1,3,4,2,5}[g] of the 6-group
  half8 af[4][4];
#pragma unroll
  for (int mt = 0; mt < 4; ++mt)
#pragma unroll
    for (int ks = 0; ks < 4; ++ks)
      af[mt][ks] = *(const half8*)&hbuf[hidx(mt * 16 + c16, ks * 32 + quad * 8)];

  for (int cls = 0; cls < 2; ++cls) {
    for (int g = 0; g < 6; ++g) {
      int pos = (g < 2) ? g : (g < 4 ? g + 1 : (g == 4 ? 2 : 5));
      half8 wf[4];
#pragma unroll
      for (int ks = 0; ks < 4; ++ks)
        wf[ks] = *(const half8*)(wsh + OFF_WX + (((cls * 6 + g) * 8 + wv) * 4 + ks) * 512 + lane * 8);
      float bv = B_enc[cls * 768 + g * 128 + d];
#pragma unroll
      for (int mt = 0; mt < 4; ++mt) {
        f32x4 acc = {0.f, 0.f, 0.f, 0.f};
#pragma unroll
        for (int ks = 0; ks < 4; ++ks)
          acc = __builtin_amdgcn_mfma_f32_16x16x32_f16(af[mt][ks], wf[ks], acc, 0, 0, 0);
#pragma unroll
        for (int r = 0; r < 4; ++r) {
          int row = mt * 16 + quad * 4 + r;
          xout[row * 768 + d * 6 + pos] = (hf)(acc[r] + actf[row] * bv);
        }
      }
    }
    __syncthreads();  // xout complete for this class
    {
      const int* src = (const int*)xout;
      int* dst = (int*)(xWb + (((size_t)cls * 64 + bn) * 192 + l0) * 768);
#pragma unroll
      for (int i = 0; i < 12; ++i) {
        int base = (t + i * 512) * 4;
        *(int4v*)&dst[base] = *(const int4v*)&src[base];
      }
    }
    __syncthreads();
  }
}

// per-wave x-gate prefetch: lane (c16, quad) covers cells c = quad*4+r at dim d
__device__ __forceinline__ void xpre_w(const hf* __restrict__ xg, int colf, int quad, int d,
                                       int sN, unsigned* pa, unsigned* pb) {
#pragma unroll
  for (int r = 0; r < 4; ++r) {
    int c = quad * 4 + r;
    int rr = sN - c;
    unsigned a = 0, b = 0;
    if (quad < 3 && rr >= 0 && rr < 16) {
      const hf* p = xg + (size_t)(rr * 12 + c) * 768 + d * 6;
      if (colf) {  // pos 3 (ushort) = u_c ; pos 4,5 (dword) = o_c, i_c
        a = (unsigned)*(const unsigned short*)(p + 3);
        b = *(const unsigned*)(p + 4);
      } else {     // pos 0,1 (dword) = u_r, o_r ; pos 2 (ushort) = i_r
        a = *(const unsigned*)p;
        b = (unsigned)*(const unsigned short*)(p + 2);
      }
    }
    pa[r] = a;
    pb[r] = b;
  }
}

// ---- kernel 3: recurrence. 1024 thr, 16 waves (4/SIMD); gates never leave MFMA
//      accumulators: in-register update per wave; A ping-pong; ONE barrier/step ----
__global__ __launch_bounds__(1024) __attribute__((amdgpu_waves_per_eu(4, 4))) void witran(
    const hf* __restrict__ wsh, const float* __restrict__ fc1_w, const float* __restrict__ fc1_b,
    const float* __restrict__ fc2_w, const float* __restrict__ fc2_b,
    const hf* __restrict__ xWb, float* __restrict__ out) {
  const int cls = blockIdx.x & 1, bn = blockIdx.x >> 1;
  const int t = threadIdx.x, lane = t & 63, wv = t >> 6;  // wv 0..15
  const int c16 = lane & 15, quad = lane >> 4;
  const int d = (wv & 7) * 16 + c16;
  const int colf = (wv >= 8);

  __shared__ __attribute__((aligned(16))) hf wlds[16 * 4096];  // 8 frags/wave (j=2, all ks)
  __shared__ __attribute__((aligned(16))) hf A[2][4096];       // ping-pong
  __shared__ float red[128];

  for (int i = t; i < 4096; i += 1024) ((int*)A)[i] = 0;  // zero both buffers

  // weights: j=0,1 (16 frags = 64 regs, AGPR-exact); j=2 -> per-wave LDS
  half8 wr[2][8];
  {
    const hf* wb = wsh + (((size_t)(cls * 16 + wv) * 3) * 8) * 512 + lane * 8;
#pragma unroll
    for (int ks = 0; ks < 8; ++ks) {
      wr[0][ks] = *(const half8*)(wb + ks * 512);
      wr[1][ks] = *(const half8*)(wb + (8 + ks) * 512);
    }
#pragma unroll
    for (int f = 0; f < 8; ++f)
      *(half8*)&wlds[wv * 4096 + f * 512 + lane * 8] = *(const half8*)(wb + (16 + f) * 512);
  }

  const hf* xg = xWb + ((size_t)cls * 64 + bn) * 192 * 768;

  unsigned pa[4], pb[4], na[4], nb[4];
  xpre_w(xg, colf, quad, d, 0, pa, pb);
  __syncthreads();  // A zero + wlds visible

  for (int s = 0; s < Steps; ++s) {
    const hf* Ac = A[s & 1];
    hf* An = A[(s + 1) & 1];

    // ---- GEMM: own gate-triple, full K=256 (reads Ac only) ----
    f32x4 a0 = {0, 0, 0, 0}, a1 = a0, a2 = a0;
#pragma unroll
    for (int ks = 0; ks < 8; ++ks) {
      half8 av = *(const half8*)&Ac[aidx(c16, ks * 32 + quad * 8)];
      a0 = __builtin_amdgcn_mfma_f32_16x16x32_f16(av, wr[0][ks], a0, 0, 0, 0);
      a1 = __builtin_amdgcn_mfma_f32_16x16x32_f16(av, wr[1][ks], a1, 0, 0, 0);
      half8 w2 = *(const half8*)&wlds[wv * 4096 + ks * 512 + lane * 8];
      a2 = __builtin_amdgcn_mfma_f32_16x16x32_f16(av, w2, a2, 0, 0, 0);
    }

    // ---- prefetch next step's x-gates (hides across update + barrier + next GEMM) ----
    xpre_w(xg, colf, quad, d, s + 1, na, nb);

    // ---- in-register update: gates are already in a0/a1/a2 for this lane's cells ----
    if (quad < 3) {
#pragma unroll
      for (int r = 0; r < 4; ++r) {
        int c = quad * 4 + r;
        if (c <= s) {  // inactive cells stay 0 / stale entries are provably overwritten
          float xu, xo, xi;
          if (colf) {
            xu = lo16f(pa[r]);  // single half in low 16
            xo = lo16f(pb[r]);
            xi = hi16f(pb[r]);
          } else {
            xu = lo16f(pa[r]);
            xo = hi16f(pa[r]);
            xi = lo16f(pb[r]);
          }
          float uu = sigmoidf_(a0[r] + xu);
          float oo = sigmoidf_(a1[r] + xo);
          float ii = tanh_(a2[r] + xi);
          float hold = (float)Ac[aidx(c, colf ? 128 + d : d)];
          float h = tanh_((1.f - uu) * hold + uu * ii) * oo;
          if (colf) {
            int c2 = (c == 11) ? 0 : c + 1;  // roll: new h_col[c] feeds slice c+1
            An[aidx(c2, 128 + d)] = (hf)h;
          } else {
            An[aidx(c, d)] = (hf)h;
          }
        }
      }
    }
    __syncthreads();  // single barrier: An complete for next step

#pragma unroll
    for (int r = 0; r < 4; ++r) { pa[r] = na[r]; pb[r] = nb[r]; }
  }

  // ---- epilogue: final state in A[Steps&1] = A[1] ----
  if (t < 128) {
    float hr = (float)A[1][aidx(11, t)];
    float hc = (float)A[1][aidx(0, 128 + t)];
    red[t] = 0.5f * (hc * fc1_w[cls * 128 + t] + hr * fc2_w[cls * 128 + t]);
  }
  __syncthreads();
  if (t == 0) {
    float sum = 0.f;
    for (int i = 0; i < 128; ++i) sum += red[i];
    out[bn * 2 + cls] = sum + 0.5f * (fc1_b[cls] + fc2_b[cls]);
  }
}

extern "C" void kernel_launch(void* const* d_in, const int* in_sizes, int n_in,
                              void* d_out, int out_size, void* d_ws, size_t ws_size,
                              hipStream_t stream) {
  const float* x = (const float*)d_in[0];
  // d_in[1] = pad_mask: unused by the reference
  const float* fc3_w = (const float*)d_in[2];
  const float* fc3_b = (const float*)d_in[3];
  const float* fc4_w = (const float*)d_in[4];
  const float* fc4_b = (const float*)d_in[5];
  const float* W_enc = (const float*)d_in[6];
  const float* B_enc = (const float*)d_in[7];
  const float* fc1_w = (const float*)d_in[8];
  const float* fc1_b = (const float*)d_in[9];
  const float* fc2_w = (const float*)d_in[10];
  const float* fc2_b = (const float*)d_in[11];
  float* out = (float*)d_out;

  hf* wsh = (hf*)d_ws;        // frag tables 1,228,800 B
  hf* xWb = wsh + OFF_XW;     // 37,748,736 B ; total 38,977,536 B

  prep<<<dim3(1200), dim3(512), 0, stream>>>(fc3_w, fc4_w, W_enc, wsh);
  prelude<<<dim3(192), dim3(512), 0, stream>>>(x, fc3_b, fc4_b, B_enc, wsh, xWb);
  witran<<<dim3(128), dim3(1024), 0, stream>>>(wsh, fc1_w, fc1_b, fc2_w, fc2_b, xWb, out);
}